// Round 1
// baseline (283.309 us; speedup 1.0000x reference)
//
#include <hip/hip_runtime.h>
#include <stdint.h>

#define B_    8
#define T_    769
#define C_    1024
#define H_    16
#define COND_ 256
#define NTOK  (B_*T_)     // 6152
#define BH_   (B_*H_)     // 128
#define TP_   896         // padded T for V^T rows (13*64 rounded to 896; mult of 8)

typedef short    v8s  __attribute__((ext_vector_type(8)));   // 8 bf16 (4 VGPRs)
typedef float    v4f  __attribute__((ext_vector_type(4)));   // 4 fp32 acc
typedef uint16_t u16x4 __attribute__((ext_vector_type(4)));
typedef uint16_t u16x8 __attribute__((ext_vector_type(8)));

__device__ __forceinline__ uint16_t f2bf(float f) {
  uint32_t u = __builtin_bit_cast(uint32_t, f);
  u += 0x7fffu + ((u >> 16) & 1u);          // RNE
  return (uint16_t)(u >> 16);
}
__device__ __forceinline__ float bf2f(uint16_t h) {
  uint32_t u = ((uint32_t)h) << 16;
  return __builtin_bit_cast(float, u);
}

// async global->LDS, 16B per lane. LDS dest must be wave-uniform base + lane*16.
__device__ __forceinline__ void gl_lds16(const void* gptr, void* lptr) {
  __builtin_amdgcn_global_load_lds(
      (const __attribute__((address_space(1))) uint32_t*)gptr,
      (__attribute__((address_space(3))) uint32_t*)lptr,
      16, 0, 0);
}

// ---------------------------------------------------------------- convert f32->bf16
__global__ __launch_bounds__(256) void convert_bf16(
    const float* xq, const float* xkv, const float* wq, const float* wk,
    const float* wv, const float* wp,
    uint16_t* dxq, uint16_t* dxkv, uint16_t* dwq, uint16_t* dwk,
    uint16_t* dwv, uint16_t* dwp)
{
  int bid = blockIdx.x;
  const float* s; uint16_t* d; int base;
  if (bid < 6152)       { s = xq;  d = dxq;  base = bid; }
  else if (bid < 12304) { s = xkv; d = dxkv; base = bid - 6152; }
  else {
    int r = bid - 12304;
    int wsel = r >> 10; base = r & 1023;
    s = (wsel == 0) ? wq : (wsel == 1) ? wk : (wsel == 2) ? wv : wp;
    d = (wsel == 0) ? dwq : (wsel == 1) ? dwk : (wsel == 2) ? dwv : dwp;
  }
  int i = base * 256 + threadIdx.x;
  float4 f = ((const float4*)s)[i];
  u16x4 o;
  o[0] = f2bf(f.x); o[1] = f2bf(f.y); o[2] = f2bf(f.z); o[3] = f2bf(f.w);
  ((u16x4*)d)[i] = o;
}

// ---------------------------------------------------------------- GEMM mainloop
// 128x128 tile, BK=64, 16 K-iters, XOR-8 chunk-swizzled LDS (0 bank conflicts).
// v2: double-buffered (T3 "minimum 2-phase"): issue next-tile global_load_lds
// BEFORE computing current tile; one vmcnt(0)+barrier per K-step (via
// __syncthreads after compute) so load latency hides under MFMA+ds_read.

__device__ __forceinline__ void gemm_stage64(
    const uint16_t* const Aptr[4], const uint16_t* const Bptr[4],
    int k0, uint16_t* sA, uint16_t* sB, int tid)
{
  #pragma unroll
  for (int r = 0; r < 4; r++) {
    gl_lds16(Aptr[r] + k0, sA + (r * 256 + tid) * 8);
    gl_lds16(Bptr[r] + k0, sB + (r * 256 + tid) * 8);
  }
}

__device__ __forceinline__ void gemm_compute64(
    const uint16_t* sAc, const uint16_t* sBc, v4f acc[4][4],
    int rbase, int cbase, int quad, int l15)
{
  #pragma unroll
  for (int s = 0; s < 2; s++) {
    v8s af[4], bfv[4];
    #pragma unroll
    for (int i = 0; i < 4; i++) {
      int m = rbase + i * 16 + l15;
      af[i] = *(const v8s*)(sAc + m * 64 + (((s * 4 + quad) ^ (m & 7)) * 8));
    }
    #pragma unroll
    for (int j = 0; j < 4; j++) {
      int n = cbase + j * 16 + l15;
      bfv[j] = *(const v8s*)(sBc + n * 64 + (((s * 4 + quad) ^ (n & 7)) * 8));
    }
    #pragma unroll
    for (int i = 0; i < 4; i++)
      #pragma unroll
      for (int j = 0; j < 4; j++)
        acc[i][j] = __builtin_amdgcn_mfma_f32_16x16x32_bf16(af[i], bfv[j], acc[i][j], 0, 0, 0);
  }
}

__device__ __forceinline__ void gemm_mainloop64(
    const uint16_t* A, const uint16_t* W, int M, int row0, int col0,
    v4f acc[4][4], uint16_t* sA, uint16_t* sB)   // sA,sB each 2*128*64
{
  const int tid = threadIdx.x;
  const int lane = tid & 63, w = tid >> 6, quad = lane >> 4, l15 = lane & 15;
  const int rbase = (w >> 1) * 64, cbase = (w & 1) * 64;

  const uint16_t* Aptr[4];
  const uint16_t* Bptr[4];
  #pragma unroll
  for (int r = 0; r < 4; r++) {
    int c = r * 256 + tid;
    int row = c >> 3, qp = c & 7;
    int g = qp ^ (row & 7);
    Aptr[r] = A + (size_t)min(row0 + row, M - 1) * 1024 + g * 8;
    Bptr[r] = W + (size_t)(col0 + row) * 1024 + g * 8;
  }

  #pragma unroll
  for (int i = 0; i < 4; i++)
    #pragma unroll
    for (int j = 0; j < 4; j++) acc[i][j] = (v4f)0.0f;

  uint16_t* sA0 = sA;         uint16_t* sB0 = sB;
  uint16_t* sA1 = sA + 8192;  uint16_t* sB1 = sB + 8192;

  // prologue: tile 0 -> buf0
  gemm_stage64(Aptr, Bptr, 0, sA0, sB0, tid);
  __syncthreads();                       // vmcnt(0) drain, once, exposed

  // 16 K-tiles, processed in pairs; each stage overlaps one compute phase.
  #pragma unroll 1
  for (int t = 0; t < 16; t += 2) {
    gemm_stage64(Aptr, Bptr, (t + 1) * 64, sA1, sB1, tid);   // tile t+1 -> buf1
    gemm_compute64(sA0, sB0, acc, rbase, cbase, quad, l15);  // compute tile t
    __syncthreads();                     // waits buf1 loads (hidden under compute)
    if (t + 2 < 16)
      gemm_stage64(Aptr, Bptr, (t + 2) * 64, sA0, sB0, tid); // tile t+2 -> buf0
    gemm_compute64(sA1, sB1, acc, rbase, cbase, quad, l15);  // compute tile t+1
    __syncthreads();
  }
}

// Fused QKV projection (Wqkv packed [3072][1024]; ct>>3 selects Q/K/V).
__global__ __launch_bounds__(256) void gemm_qkv(
    const uint16_t* xq, const uint16_t* xkv, const uint16_t* Wqkv,
    const float* bq, const float* bk, const float* bv, const float* freqs,
    uint16_t* Q, uint16_t* K, uint16_t* V)
{
  __shared__ uint16_t sA[2 * 128 * 64];
  __shared__ uint16_t sB[2 * 128 * 64];
  const int ct = blockIdx.x, rt = blockIdx.y;
  const int z = ct >> 3;
  const int col0 = ct * 128, row0 = rt * 128;
  const uint16_t* A = (z == 0) ? xq : xkv;
  const float* bias  = (z == 0) ? bq : (z == 1 ? bk : bv);
  uint16_t* dst      = (z == 0) ? Q  : (z == 1 ? K  : V);

  v4f acc[4][4];
  gemm_mainloop64(A, Wqkv, NTOK, row0, col0, acc, sA, sB);

  const int tid = threadIdx.x;
  const int lane = tid & 63, w = tid >> 6, quad = lane >> 4, l15 = lane & 15;
  const int rbase = (w >> 1) * 64, cbase = (w & 1) * 64;
  #pragma unroll
  for (int i = 0; i < 4; i++) {
    #pragma unroll
    for (int reg = 0; reg < 4; reg++) {
      int n = row0 + rbase + i * 16 + quad * 4 + reg;
      bool ok = (n < NTOK);
      int nn = min(n, NTOK - 1);
      int b = nn / T_, t = nn % T_;
      float vj[4];
      #pragma unroll
      for (int j = 0; j < 4; j++)
        vj[j] = acc[i][j][reg] + bias[(col0 + cbase + j * 16 + l15) & 1023];
      if (z < 2) {
        float v0 = vj[0], v1 = vj[1];
        float p0 = __shfl_xor(v0, 1);
        float p1 = __shfl_xor(v1, 1);
        float f0 = freqs[t * 32 + l15];
        float f1 = freqs[t * 32 + 16 + l15];
        float s0, c0, s1, c1;
        __sincosf(f0, &s0, &c0);
        __sincosf(f1, &s1, &c1);
        if (l15 & 1) { vj[0] = v0 * c0 + p0 * s0; vj[1] = v1 * c1 + p1 * s1; }
        else         { vj[0] = v0 * c0 - p0 * s0; vj[1] = v1 * c1 - p1 * s1; }
      }
      if (z == 0) {
        #pragma unroll
        for (int j = 0; j < 4; j++) vj[j] *= 0.125f;
      }
      if (ok) {
        #pragma unroll
        for (int j = 0; j < 4; j++) {
          int col = col0 + cbase + j * 16 + l15;
          int h = (col >> 6) & 15, d = col & 63;
          dst[((size_t)(b * H_ + h) * T_ + t) * 64 + d] = f2bf(vj[j]);
        }
      }
    }
  }
}

// Output projection: f32 -> d_out [NTOK][1024]
__global__ __launch_bounds__(256) void gemm_out(
    const uint16_t* Y, const uint16_t* wp, const float* bp, float* out)
{
  __shared__ uint16_t sA[2 * 128 * 64];
  __shared__ uint16_t sB[2 * 128 * 64];
  const int col0 = blockIdx.x * 128, row0 = blockIdx.y * 128;
  v4f acc[4][4];
  gemm_mainloop64(Y, wp, NTOK, row0, col0, acc, sA, sB);

  const int tid = threadIdx.x;
  const int lane = tid & 63, w = tid >> 6, quad = lane >> 4, l15 = lane & 15;
  const int rbase = (w >> 1) * 64, cbase = (w & 1) * 64;
  #pragma unroll
  for (int i = 0; i < 4; i++) {
    #pragma unroll
    for (int reg = 0; reg < 4; reg++) {
      int n = row0 + rbase + i * 16 + quad * 4 + reg;
      if (n < NTOK) {
        #pragma unroll
        for (int j = 0; j < 4; j++) {
          int col = col0 + cbase + j * 16 + l15;
          out[(size_t)n * 1024 + col] = acc[i][j][reg] + bp[col];
        }
      }
    }
  }
}

// ---------------------------------------------------------------- V transpose
// Vb [bh][T][64] -> Vt [bh][64][TP_]. 64x64 tiles, XOR-swizzled LDS (8 KB).
// Both global sides coalesced (128B runs); LDS read side conflict-free.
__global__ __launch_bounds__(256) void transpose_v(const uint16_t* Vb, uint16_t* Vt)
{
  __shared__ uint16_t sT[64 * 64];
  const int tid = threadIdx.x;
  const int t0 = blockIdx.x * 64, bh = blockIdx.y;
  const uint16_t* src = Vb + (size_t)bh * T_ * 64;
  #pragma unroll
  for (int r = 0; r < 2; r++) {
    int task = r * 256 + tid;
    int t = task >> 3, oc = task & 7;
    int gt = min(t0 + t, T_ - 1);
    u16x8 v = *(const u16x8*)(src + (size_t)gt * 64 + oc * 8);
    int p = oc ^ (t & 7) ^ ((t >> 3) & 7);
    *(u16x8*)(sT + t * 64 + p * 8) = v;
  }
  __syncthreads();
  uint16_t* dst = Vt + (size_t)bh * 64 * TP_;
  #pragma unroll
  for (int r = 0; r < 2; r++) {
    int task = r * 256 + tid;
    int o = task & 7, d = task >> 3;
    u16x8 v;
    #pragma unroll
    for (int k = 0; k < 8; k++) {
      int t = o * 8 + k;
      int p = (d >> 3) ^ k ^ o;
      v[k] = sT[t * 64 + p * 8 + (d & 7)];
    }
    *(u16x8*)(dst + (size_t)d * TP_ + t0 + o * 8) = v;
  }
}

// ---------------------------------------------------------------- flash attention
// 4 waves x 16 q-rows; 128-key tiles; fixed-max softmax.
// sK [128 keys][64 d] and sVT [64 d][128 keys] both gl_lds16-staged with
// XOR-8 chunk swizzle (2-way bank aliasing = free). sP per-wave [16][136].
__global__ __launch_bounds__(256) void attn(
    const uint16_t* Q, const uint16_t* K, const uint16_t* Vt, uint16_t* Y)
{
  __shared__ uint16_t sK[128 * 64];
  __shared__ uint16_t sVT[64 * 128];
  __shared__ uint16_t sP[4 * 16 * 136];

  const int tid = threadIdx.x;
  const int lane = tid & 63, w = tid >> 6, quad = lane >> 4, l15 = lane & 15;
  const int bh = blockIdx.y, b = bh >> 4, h = bh & 15;
  const int q0 = blockIdx.x * 64;

  const uint16_t* Qb = Q + (size_t)bh * T_ * 64;
  const uint16_t* Kb = K + (size_t)bh * T_ * 64;
  const uint16_t* Vtb = Vt + (size_t)bh * 64 * TP_;

  const int qr = min(q0 + w * 16 + l15, T_ - 1);
  v8s aq0 = *(const v8s*)(Qb + (size_t)qr * 64 + quad * 8);
  v8s aq1 = *(const v8s*)(Qb + (size_t)qr * 64 + 32 + quad * 8);

  float l_r[4] = {0.f, 0.f, 0.f, 0.f};
  v4f o[4];
  #pragma unroll
  for (int r = 0; r < 4; r++) o[r] = (v4f)0.0f;

  const int kend = min(T_, q0 + 319);       // max col = 255 + (q0+63)
  const int nkt = (kend + 127) >> 7;

  for (int kt = 0; kt < nkt; kt++) {
    const int k0 = kt * 128;
    // --- stage K tile (natural layout, XOR-8 swizzle)
    #pragma unroll
    for (int r = 0; r < 4; r++) {
      int c = r * 256 + tid;
      int key = c >> 3, qp = c & 7;
      int g = qp ^ (key & 7);
      int gk = min(k0 + key, T_ - 1);
      gl_lds16(Kb + (size_t)gk * 64 + g * 8, sK + c * 8);
    }
    // --- stage V^T tile (pre-transposed global, XOR-8 swizzle on 16 chunks/row)
    #pragma unroll
    for (int r = 0; r < 4; r++) {
      int c = r * 256 + tid;
      int d = c >> 4, p = c & 15;
      int g = (p & 8) | ((p ^ d) & 7);
      gl_lds16(Vtb + (size_t)d * TP_ + k0 + g * 8, sVT + c * 8);
    }
    __syncthreads();

    // --- S = Q K^T (Q pre-scaled by 1/8): 8 key frags x 2 k-steps
    v4f s[8];
    #pragma unroll
    for (int cb = 0; cb < 8; cb++) {
      int key_l = cb * 16 + l15;
      v8s b0 = *(const v8s*)(sK + (key_l * 8 + ((quad) ^ (key_l & 7))) * 8);
      v8s b1 = *(const v8s*)(sK + (key_l * 8 + ((4 + quad) ^ (key_l & 7))) * 8);
      v4f zz = (v4f)0.0f;
      zz = __builtin_amdgcn_mfma_f32_16x16x32_bf16(aq0, b0, zz, 0, 0, 0);
      zz = __builtin_amdgcn_mfma_f32_16x16x32_bf16(aq1, b1, zz, 0, 0, 0);
      s[cb] = zz;
    }

    // --- fixed-max softmax: P = exp(S), masked -> 0
    uint16_t* pw = sP + w * (16 * 136);
    const int qrow_base = q0 + w * 16 + quad * 4;
    const bool full = (k0 + 128 <= COND_ + q0) && (k0 + 128 <= T_);
    if (full) {
      #pragma unroll
      for (int reg = 0; reg < 4; reg++) {
        float rs = 0.f;
        #pragma unroll
        for (int cb = 0; cb < 8; cb++) {
          float pv = __expf(s[cb][reg]);
          uint16_t pb = f2bf(pv);
          rs += bf2f(pb);
          pw[(quad * 4 + reg) * 136 + cb * 16 + l15] = pb;
        }
        #pragma unroll
        for (int off = 1; off < 16; off <<= 1) rs += __shfl_xor(rs, off);
        l_r[reg] += rs;
      }
    } else {
      #pragma unroll
      for (int reg = 0; reg < 4; reg++) {
        int lim = min(COND_ + qrow_base + reg, T_);
        float rs = 0.f;
        #pragma unroll
        for (int cb = 0; cb < 8; cb++) {
          int key = k0 + cb * 16 + l15;
          float pv = (key < lim) ? __expf(s[cb][reg]) : 0.f;
          uint16_t pb = f2bf(pv);
          rs += bf2f(pb);
          pw[(quad * 4 + reg) * 136 + cb * 16 + l15] = pb;
        }
        #pragma unroll
        for (int off = 1; off < 16; off <<= 1) rs += __shfl_xor(rs, off);
        l_r[reg] += rs;
      }
    }

    // --- O += P V (sP wave-private; in-wave lgkm ordering suffices)
    #pragma unroll
    for (int ks = 0; ks < 4; ks++) {
      v8s ap = *(const v8s*)(pw + l15 * 136 + ks * 32 + quad * 8);
      #pragma unroll
      for (int cbd = 0; cbd < 4; cbd++) {
        int d = cbd * 16 + l15;
        v8s bv = *(const v8s*)(sVT + d * 128 + (((ks * 4 + quad) ^ (d & 7)) * 8));
        o[cbd] = __builtin_amdgcn_mfma_f32_16x16x32_bf16(ap, bv, o[cbd], 0, 0, 0);
      }
    }
    __syncthreads();   // safe to restage K/V next iter
  }

  // --- epilogue: O / l -> Y [B][T][C] bf16
  #pragma unroll
  for (int reg = 0; reg < 4; reg++) {
    int t = q0 + w * 16 + quad * 4 + reg;
    if (t < T_) {
      float inv = 1.0f / l_r[reg];
      #pragma unroll
      for (int cbd = 0; cbd < 4; cbd++) {
        int d = cbd * 16 + l15;
        Y[((size_t)(b * T_ + t)) * C_ + h * 64 + d] = f2bf(o[cbd][reg] * inv);
      }
    }
  }
}

// ---------------------------------------------------------------- launch
extern "C" void kernel_launch(void* const* d_in, const int* in_sizes, int n_in,
                              void* d_out, int out_size, void* d_ws, size_t ws_size,
                              hipStream_t stream)
{
  const float* x_q   = (const float*)d_in[0];
  const float* x_kv  = (const float*)d_in[1];
  const float* freqs = (const float*)d_in[2];
  const float* Wq = (const float*)d_in[3];
  const float* bq = (const float*)d_in[4];
  const float* Wk = (const float*)d_in[5];
  const float* bk = (const float*)d_in[6];
  const float* Wv = (const float*)d_in[7];
  const float* bv = (const float*)d_in[8];
  const float* Wp = (const float*)d_in[9];
  const float* bp = (const float*)d_in[10];
  float* out = (float*)d_out;

  const size_t SZX = (size_t)NTOK * C_;     // 6,299,648
  const size_t SZW = (size_t)C_ * C_;       // 1,048,576
  uint16_t* ws = (uint16_t*)d_ws;
  // layout: [xq_bf | xkv_bf | wq wk wv wp | Qb | Kb | Vb]  (71.4 MB total)
  uint16_t* xq_bf  = ws;
  uint16_t* xkv_bf = xq_bf + SZX;
  uint16_t* wq_bf  = xkv_bf + SZX;   // wq/wk/wv contiguous = packed Wqkv[3072][1024]
  uint16_t* wk_bf  = wq_bf + SZW;
  uint16_t* wv_bf  = wk_bf + SZW;
  uint16_t* wp_bf  = wv_bf + SZW;
  uint16_t* Qb = wp_bf + SZW;
  uint16_t* Kb = Qb + SZX;
  uint16_t* Vb = Kb + SZX;
  // aliases (lifetimes disjoint on the serial stream):
  uint16_t* Vt = ws;                 // 128*64*896 = 7.34M elems over dead xq/xkv
  uint16_t* Yb = Vb;                 // attn output over dead natural-V

  convert_bf16<<<dim3(16400), 256, 0, stream>>>(
      x_q, x_kv, Wq, Wk, Wv, Wp, xq_bf, xkv_bf, wq_bf, wk_bf, wv_bf, wp_bf);

  gemm_qkv<<<dim3(24, 49), 256, 0, stream>>>(
      xq_bf, xkv_bf, wq_bf, bq, bk, bv, freqs, Qb, Kb, Vb);

  transpose_v<<<dim3(13, BH_), 256, 0, stream>>>(Vb, Vt);

  attn<<<dim3(13, BH_), 256, 0, stream>>>(Qb, Kb, Vt, Yb);

  gemm_out<<<dim3(8, 49), 256, 0, stream>>>(Yb, wp_bf, bp, out);
}

// Round 2
// 274.548 us; speedup vs baseline: 1.0319x; 1.0319x over previous
//
#include <hip/hip_runtime.h>
#include <stdint.h>

#define B_    8
#define T_    769
#define C_    1024
#define H_    16
#define COND_ 256
#define NTOK  (B_*T_)     // 6152
#define BH_   (B_*H_)     // 128
#define TP_   896         // padded T for V^T rows (13*64 rounded to 896; mult of 8)

typedef short    v8s  __attribute__((ext_vector_type(8)));   // 8 bf16 (4 VGPRs)
typedef float    v4f  __attribute__((ext_vector_type(4)));   // 4 fp32 acc
typedef uint16_t u16x4 __attribute__((ext_vector_type(4)));
typedef uint16_t u16x8 __attribute__((ext_vector_type(8)));

__device__ __forceinline__ uint16_t f2bf(float f) {
  uint32_t u = __builtin_bit_cast(uint32_t, f);
  u += 0x7fffu + ((u >> 16) & 1u);          // RNE
  return (uint16_t)(u >> 16);
}
__device__ __forceinline__ float bf2f(uint16_t h) {
  uint32_t u = ((uint32_t)h) << 16;
  return __builtin_bit_cast(float, u);
}

// async global->LDS, 16B per lane. LDS dest must be wave-uniform base + lane*16.
__device__ __forceinline__ void gl_lds16(const void* gptr, void* lptr) {
  __builtin_amdgcn_global_load_lds(
      (const __attribute__((address_space(1))) uint32_t*)gptr,
      (__attribute__((address_space(3))) uint32_t*)lptr,
      16, 0, 0);
}

// ---------------------------------------------------------------- convert f32->bf16
__global__ __launch_bounds__(256) void convert_bf16(
    const float* xq, const float* xkv, const float* wq, const float* wk,
    const float* wv, const float* wp,
    uint16_t* dxq, uint16_t* dxkv, uint16_t* dwq, uint16_t* dwk,
    uint16_t* dwv, uint16_t* dwp)
{
  int bid = blockIdx.x;
  const float* s; uint16_t* d; int base;
  if (bid < 6152)       { s = xq;  d = dxq;  base = bid; }
  else if (bid < 12304) { s = xkv; d = dxkv; base = bid - 6152; }
  else {
    int r = bid - 12304;
    int wsel = r >> 10; base = r & 1023;
    s = (wsel == 0) ? wq : (wsel == 1) ? wk : (wsel == 2) ? wv : wp;
    d = (wsel == 0) ? dwq : (wsel == 1) ? dwk : (wsel == 2) ? dwv : dwp;
  }
  int i = base * 256 + threadIdx.x;
  float4 f = ((const float4*)s)[i];
  u16x4 o;
  o[0] = f2bf(f.x); o[1] = f2bf(f.y); o[2] = f2bf(f.z); o[3] = f2bf(f.w);
  ((u16x4*)d)[i] = o;
}

// ---------------------------------------------------------------- GEMM mainloop
// 128x128 tile, BK=64, 16 K-iters, XOR-8 chunk-swizzled LDS (0 bank conflicts).
// v3 (T3+T4 minimum form): 2-deep pipeline with COUNTED vmcnt + raw s_barrier.
// vmcnt(8) keeps the next tile's 8 global_load_lds in flight ACROSS barriers;
// vmcnt never drains to 0 inside the loop (m218: counted-vs-drain0 = +38-73%).

__device__ __forceinline__ void gemm_stage64(
    const uint16_t* const Aptr[4], const uint16_t* const Bptr[4],
    int k0, uint16_t* sA, uint16_t* sB, int tid)
{
  #pragma unroll
  for (int r = 0; r < 4; r++) {
    gl_lds16(Aptr[r] + k0, sA + (r * 256 + tid) * 8);
    gl_lds16(Bptr[r] + k0, sB + (r * 256 + tid) * 8);
  }
}

__device__ __forceinline__ void gemm_compute64(
    const uint16_t* sAc, const uint16_t* sBc, v4f acc[4][4],
    int rbase, int cbase, int quad, int l15)
{
  #pragma unroll
  for (int s = 0; s < 2; s++) {
    v8s af[4], bfv[4];
    #pragma unroll
    for (int i = 0; i < 4; i++) {
      int m = rbase + i * 16 + l15;
      af[i] = *(const v8s*)(sAc + m * 64 + (((s * 4 + quad) ^ (m & 7)) * 8));
    }
    #pragma unroll
    for (int j = 0; j < 4; j++) {
      int n = cbase + j * 16 + l15;
      bfv[j] = *(const v8s*)(sBc + n * 64 + (((s * 4 + quad) ^ (n & 7)) * 8));
    }
    #pragma unroll
    for (int i = 0; i < 4; i++)
      #pragma unroll
      for (int j = 0; j < 4; j++)
        acc[i][j] = __builtin_amdgcn_mfma_f32_16x16x32_bf16(af[i], bfv[j], acc[i][j], 0, 0, 0);
  }
}

__device__ __forceinline__ void gemm_mainloop64(
    const uint16_t* A, const uint16_t* W, int M, int row0, int col0,
    v4f acc[4][4], uint16_t* sA, uint16_t* sB)   // sA,sB each 2*128*64
{
  const int tid = threadIdx.x;
  const int lane = tid & 63, w = tid >> 6, quad = lane >> 4, l15 = lane & 15;
  const int rbase = (w >> 1) * 64, cbase = (w & 1) * 64;

  const uint16_t* Aptr[4];
  const uint16_t* Bptr[4];
  #pragma unroll
  for (int r = 0; r < 4; r++) {
    int c = r * 256 + tid;
    int row = c >> 3, qp = c & 7;
    int g = qp ^ (row & 7);
    Aptr[r] = A + (size_t)min(row0 + row, M - 1) * 1024 + g * 8;
    Bptr[r] = W + (size_t)(col0 + row) * 1024 + g * 8;
  }

  #pragma unroll
  for (int i = 0; i < 4; i++)
    #pragma unroll
    for (int j = 0; j < 4; j++) acc[i][j] = (v4f)0.0f;

  uint16_t* sA0 = sA;         uint16_t* sB0 = sB;
  uint16_t* sA1 = sA + 8192;  uint16_t* sB1 = sB + 8192;

  // prologue: stage tiles 0 and 1 (16 loads in flight per wave)
  gemm_stage64(Aptr, Bptr, 0,  sA0, sB0, tid);
  gemm_stage64(Aptr, Bptr, 64, sA1, sB1, tid);

  #pragma unroll 1
  for (int t = 0; t < 16; t++) {
    // Wait for THIS tile's 8 loads only; tile t+1's 8 stay in flight.
    if (t < 15) {
      asm volatile("s_waitcnt vmcnt(8)" ::: "memory");
    } else {
      asm volatile("s_waitcnt vmcnt(0)" ::: "memory");
    }
    __builtin_amdgcn_s_barrier();        // all waves' tile-t loads have landed
    uint16_t* cA = (t & 1) ? sA1 : sA0;
    uint16_t* cB = (t & 1) ? sB1 : sB0;
    gemm_compute64(cA, cB, acc, rbase, cbase, quad, l15);
    __builtin_amdgcn_s_barrier();        // all waves done reading buf[t&1]
    if (t + 2 < 16)
      gemm_stage64(Aptr, Bptr, (t + 2) * 64, cA, cB, tid);  // restage consumed buf
  }
}

// Fused QKV projection (Wqkv packed [3072][1024]; ct>>3 selects Q/K/V).
__global__ __launch_bounds__(256) void gemm_qkv(
    const uint16_t* xq, const uint16_t* xkv, const uint16_t* Wqkv,
    const float* bq, const float* bk, const float* bv, const float* freqs,
    uint16_t* Q, uint16_t* K, uint16_t* V)
{
  __shared__ uint16_t sA[2 * 128 * 64];
  __shared__ uint16_t sB[2 * 128 * 64];
  const int ct = blockIdx.x, rt = blockIdx.y;
  const int z = ct >> 3;
  const int col0 = ct * 128, row0 = rt * 128;
  const uint16_t* A = (z == 0) ? xq : xkv;
  const float* bias  = (z == 0) ? bq : (z == 1 ? bk : bv);
  uint16_t* dst      = (z == 0) ? Q  : (z == 1 ? K  : V);

  v4f acc[4][4];
  gemm_mainloop64(A, Wqkv, NTOK, row0, col0, acc, sA, sB);

  const int tid = threadIdx.x;
  const int lane = tid & 63, w = tid >> 6, quad = lane >> 4, l15 = lane & 15;
  const int rbase = (w >> 1) * 64, cbase = (w & 1) * 64;
  #pragma unroll
  for (int i = 0; i < 4; i++) {
    #pragma unroll
    for (int reg = 0; reg < 4; reg++) {
      int n = row0 + rbase + i * 16 + quad * 4 + reg;
      bool ok = (n < NTOK);
      int nn = min(n, NTOK - 1);
      int b = nn / T_, t = nn % T_;
      float vj[4];
      #pragma unroll
      for (int j = 0; j < 4; j++)
        vj[j] = acc[i][j][reg] + bias[(col0 + cbase + j * 16 + l15) & 1023];
      if (z < 2) {
        float v0 = vj[0], v1 = vj[1];
        float p0 = __shfl_xor(v0, 1);
        float p1 = __shfl_xor(v1, 1);
        float f0 = freqs[t * 32 + l15];
        float f1 = freqs[t * 32 + 16 + l15];
        float s0, c0, s1, c1;
        __sincosf(f0, &s0, &c0);
        __sincosf(f1, &s1, &c1);
        if (l15 & 1) { vj[0] = v0 * c0 + p0 * s0; vj[1] = v1 * c1 + p1 * s1; }
        else         { vj[0] = v0 * c0 - p0 * s0; vj[1] = v1 * c1 - p1 * s1; }
      }
      if (z == 0) {
        #pragma unroll
        for (int j = 0; j < 4; j++) vj[j] *= 0.125f;
      }
      if (ok) {
        #pragma unroll
        for (int j = 0; j < 4; j++) {
          int col = col0 + cbase + j * 16 + l15;
          int h = (col >> 6) & 15, d = col & 63;
          dst[((size_t)(b * H_ + h) * T_ + t) * 64 + d] = f2bf(vj[j]);
        }
      }
    }
  }
}

// Output projection: f32 -> d_out [NTOK][1024]
__global__ __launch_bounds__(256) void gemm_out(
    const uint16_t* Y, const uint16_t* wp, const float* bp, float* out)
{
  __shared__ uint16_t sA[2 * 128 * 64];
  __shared__ uint16_t sB[2 * 128 * 64];
  const int col0 = blockIdx.x * 128, row0 = blockIdx.y * 128;
  v4f acc[4][4];
  gemm_mainloop64(Y, wp, NTOK, row0, col0, acc, sA, sB);

  const int tid = threadIdx.x;
  const int lane = tid & 63, w = tid >> 6, quad = lane >> 4, l15 = lane & 15;
  const int rbase = (w >> 1) * 64, cbase = (w & 1) * 64;
  #pragma unroll
  for (int i = 0; i < 4; i++) {
    #pragma unroll
    for (int reg = 0; reg < 4; reg++) {
      int n = row0 + rbase + i * 16 + quad * 4 + reg;
      if (n < NTOK) {
        #pragma unroll
        for (int j = 0; j < 4; j++) {
          int col = col0 + cbase + j * 16 + l15;
          out[(size_t)n * 1024 + col] = acc[i][j][reg] + bp[col];
        }
      }
    }
  }
}

// ---------------------------------------------------------------- V transpose
// Vb [bh][T][64] -> Vt [bh][64][TP_]. 64x64 tiles, XOR-swizzled LDS (8 KB).
// Both global sides coalesced (128B runs); LDS read side conflict-free.
__global__ __launch_bounds__(256) void transpose_v(const uint16_t* Vb, uint16_t* Vt)
{
  __shared__ uint16_t sT[64 * 64];
  const int tid = threadIdx.x;
  const int t0 = blockIdx.x * 64, bh = blockIdx.y;
  const uint16_t* src = Vb + (size_t)bh * T_ * 64;
  #pragma unroll
  for (int r = 0; r < 2; r++) {
    int task = r * 256 + tid;
    int t = task >> 3, oc = task & 7;
    int gt = min(t0 + t, T_ - 1);
    u16x8 v = *(const u16x8*)(src + (size_t)gt * 64 + oc * 8);
    int p = oc ^ (t & 7) ^ ((t >> 3) & 7);
    *(u16x8*)(sT + t * 64 + p * 8) = v;
  }
  __syncthreads();
  uint16_t* dst = Vt + (size_t)bh * 64 * TP_;
  #pragma unroll
  for (int r = 0; r < 2; r++) {
    int task = r * 256 + tid;
    int o = task & 7, d = task >> 3;
    u16x8 v;
    #pragma unroll
    for (int k = 0; k < 8; k++) {
      int t = o * 8 + k;
      int p = (d >> 3) ^ k ^ o;
      v[k] = sT[t * 64 + p * 8 + (d & 7)];
    }
    *(u16x8*)(dst + (size_t)d * TP_ + t0 + o * 8) = v;
  }
}

// ---------------------------------------------------------------- flash attention
// 4 waves x 16 q-rows; 128-key tiles; fixed-max softmax.
// sK [128 keys][64 d] and sVT [64 d][128 keys] both gl_lds16-staged with
// XOR-8 chunk swizzle (2-way bank aliasing = free). sP per-wave [16][136].
__global__ __launch_bounds__(256) void attn(
    const uint16_t* Q, const uint16_t* K, const uint16_t* Vt, uint16_t* Y)
{
  __shared__ uint16_t sK[128 * 64];
  __shared__ uint16_t sVT[64 * 128];
  __shared__ uint16_t sP[4 * 16 * 136];

  const int tid = threadIdx.x;
  const int lane = tid & 63, w = tid >> 6, quad = lane >> 4, l15 = lane & 15;
  const int bh = blockIdx.y, b = bh >> 4, h = bh & 15;
  const int q0 = blockIdx.x * 64;

  const uint16_t* Qb = Q + (size_t)bh * T_ * 64;
  const uint16_t* Kb = K + (size_t)bh * T_ * 64;
  const uint16_t* Vtb = Vt + (size_t)bh * 64 * TP_;

  const int qr = min(q0 + w * 16 + l15, T_ - 1);
  v8s aq0 = *(const v8s*)(Qb + (size_t)qr * 64 + quad * 8);
  v8s aq1 = *(const v8s*)(Qb + (size_t)qr * 64 + 32 + quad * 8);

  float l_r[4] = {0.f, 0.f, 0.f, 0.f};
  v4f o[4];
  #pragma unroll
  for (int r = 0; r < 4; r++) o[r] = (v4f)0.0f;

  const int kend = min(T_, q0 + 319);       // max col = 255 + (q0+63)
  const int nkt = (kend + 127) >> 7;

  for (int kt = 0; kt < nkt; kt++) {
    const int k0 = kt * 128;
    // --- stage K tile (natural layout, XOR-8 swizzle)
    #pragma unroll
    for (int r = 0; r < 4; r++) {
      int c = r * 256 + tid;
      int key = c >> 3, qp = c & 7;
      int g = qp ^ (key & 7);
      int gk = min(k0 + key, T_ - 1);
      gl_lds16(Kb + (size_t)gk * 64 + g * 8, sK + c * 8);
    }
    // --- stage V^T tile (pre-transposed global, XOR-8 swizzle on 16 chunks/row)
    #pragma unroll
    for (int r = 0; r < 4; r++) {
      int c = r * 256 + tid;
      int d = c >> 4, p = c & 15;
      int g = (p & 8) | ((p ^ d) & 7);
      gl_lds16(Vtb + (size_t)d * TP_ + k0 + g * 8, sVT + c * 8);
    }
    __syncthreads();

    // --- S = Q K^T (Q pre-scaled by 1/8): 8 key frags x 2 k-steps
    v4f s[8];
    #pragma unroll
    for (int cb = 0; cb < 8; cb++) {
      int key_l = cb * 16 + l15;
      v8s b0 = *(const v8s*)(sK + (key_l * 8 + ((quad) ^ (key_l & 7))) * 8);
      v8s b1 = *(const v8s*)(sK + (key_l * 8 + ((4 + quad) ^ (key_l & 7))) * 8);
      v4f zz = (v4f)0.0f;
      zz = __builtin_amdgcn_mfma_f32_16x16x32_bf16(aq0, b0, zz, 0, 0, 0);
      zz = __builtin_amdgcn_mfma_f32_16x16x32_bf16(aq1, b1, zz, 0, 0, 0);
      s[cb] = zz;
    }

    // --- fixed-max softmax: P = exp(S), masked -> 0
    uint16_t* pw = sP + w * (16 * 136);
    const int qrow_base = q0 + w * 16 + quad * 4;
    const bool full = (k0 + 128 <= COND_ + q0) && (k0 + 128 <= T_);
    if (full) {
      #pragma unroll
      for (int reg = 0; reg < 4; reg++) {
        float rs = 0.f;
        #pragma unroll
        for (int cb = 0; cb < 8; cb++) {
          float pv = __expf(s[cb][reg]);
          uint16_t pb = f2bf(pv);
          rs += bf2f(pb);
          pw[(quad * 4 + reg) * 136 + cb * 16 + l15] = pb;
        }
        #pragma unroll
        for (int off = 1; off < 16; off <<= 1) rs += __shfl_xor(rs, off);
        l_r[reg] += rs;
      }
    } else {
      #pragma unroll
      for (int reg = 0; reg < 4; reg++) {
        int lim = min(COND_ + qrow_base + reg, T_);
        float rs = 0.f;
        #pragma unroll
        for (int cb = 0; cb < 8; cb++) {
          int key = k0 + cb * 16 + l15;
          float pv = (key < lim) ? __expf(s[cb][reg]) : 0.f;
          uint16_t pb = f2bf(pv);
          rs += bf2f(pb);
          pw[(quad * 4 + reg) * 136 + cb * 16 + l15] = pb;
        }
        #pragma unroll
        for (int off = 1; off < 16; off <<= 1) rs += __shfl_xor(rs, off);
        l_r[reg] += rs;
      }
    }

    // --- O += P V (sP wave-private; in-wave lgkm ordering suffices)
    #pragma unroll
    for (int ks = 0; ks < 4; ks++) {
      v8s ap = *(const v8s*)(pw + l15 * 136 + ks * 32 + quad * 8);
      #pragma unroll
      for (int cbd = 0; cbd < 4; cbd++) {
        int d = cbd * 16 + l15;
        v8s bv = *(const v8s*)(sVT + d * 128 + (((ks * 4 + quad) ^ (d & 7)) * 8));
        o[cbd] = __builtin_amdgcn_mfma_f32_16x16x32_bf16(ap, bv, o[cbd], 0, 0, 0);
      }
    }
    __syncthreads();   // safe to restage K/V next iter
  }

  // --- epilogue: O / l -> Y [B][T][C] bf16
  #pragma unroll
  for (int reg = 0; reg < 4; reg++) {
    int t = q0 + w * 16 + quad * 4 + reg;
    if (t < T_) {
      float inv = 1.0f / l_r[reg];
      #pragma unroll
      for (int cbd = 0; cbd < 4; cbd++) {
        int d = cbd * 16 + l15;
        Y[((size_t)(b * T_ + t)) * C_ + h * 64 + d] = f2bf(o[cbd][reg] * inv);
      }
    }
  }
}

// ---------------------------------------------------------------- launch
extern "C" void kernel_launch(void* const* d_in, const int* in_sizes, int n_in,
                              void* d_out, int out_size, void* d_ws, size_t ws_size,
                              hipStream_t stream)
{
  const float* x_q   = (const float*)d_in[0];
  const float* x_kv  = (const float*)d_in[1];
  const float* freqs = (const float*)d_in[2];
  const float* Wq = (const float*)d_in[3];
  const float* bq = (const float*)d_in[4];
  const float* Wk = (const float*)d_in[5];
  const float* bk = (const float*)d_in[6];
  const float* Wv = (const float*)d_in[7];
  const float* bv = (const float*)d_in[8];
  const float* Wp = (const float*)d_in[9];
  const float* bp = (const float*)d_in[10];
  float* out = (float*)d_out;

  const size_t SZX = (size_t)NTOK * C_;     // 6,299,648
  const size_t SZW = (size_t)C_ * C_;       // 1,048,576
  uint16_t* ws = (uint16_t*)d_ws;
  // layout: [xq_bf | xkv_bf | wq wk wv wp | Qb | Kb | Vb]  (71.4 MB total)
  uint16_t* xq_bf  = ws;
  uint16_t* xkv_bf = xq_bf + SZX;
  uint16_t* wq_bf  = xkv_bf + SZX;   // wq/wk/wv contiguous = packed Wqkv[3072][1024]
  uint16_t* wk_bf  = wq_bf + SZW;
  uint16_t* wv_bf  = wk_bf + SZW;
  uint16_t* wp_bf  = wv_bf + SZW;
  uint16_t* Qb = wp_bf + SZW;
  uint16_t* Kb = Qb + SZX;
  uint16_t* Vb = Kb + SZX;
  // aliases (lifetimes disjoint on the serial stream):
  uint16_t* Vt = ws;                 // 128*64*896 = 7.34M elems over dead xq/xkv
  uint16_t* Yb = Vb;                 // attn output over dead natural-V

  convert_bf16<<<dim3(16400), 256, 0, stream>>>(
      x_q, x_kv, Wq, Wk, Wv, Wp, xq_bf, xkv_bf, wq_bf, wk_bf, wv_bf, wp_bf);

  gemm_qkv<<<dim3(24, 49), 256, 0, stream>>>(
      xq_bf, xkv_bf, wq_bf, bq, bk, bv, freqs, Qb, Kb, Vb);

  transpose_v<<<dim3(13, BH_), 256, 0, stream>>>(Vb, Vt);

  attn<<<dim3(13, BH_), 256, 0, stream>>>(Qb, Kb, Vt, Yb);

  gemm_out<<<dim3(8, 49), 256, 0, stream>>>(Yb, wp_bf, bp, out);
}

// Round 3
// 272.407 us; speedup vs baseline: 1.0400x; 1.0079x over previous
//
#include <hip/hip_runtime.h>
#include <stdint.h>

#define B_    8
#define T_    769
#define C_    1024
#define H_    16
#define COND_ 256
#define NTOK  (B_*T_)     // 6152
#define BH_   (B_*H_)     // 128
#define TP_   896         // padded T for V^T rows (13*64 rounded to 896; mult of 8)

typedef short    v8s  __attribute__((ext_vector_type(8)));   // 8 bf16 (4 VGPRs)
typedef float    v4f  __attribute__((ext_vector_type(4)));   // 4 fp32 acc
typedef uint16_t u16x4 __attribute__((ext_vector_type(4)));
typedef uint16_t u16x8 __attribute__((ext_vector_type(8)));

__device__ __forceinline__ uint16_t f2bf(float f) {
  uint32_t u = __builtin_bit_cast(uint32_t, f);
  u += 0x7fffu + ((u >> 16) & 1u);          // RNE
  return (uint16_t)(u >> 16);
}
__device__ __forceinline__ float bf2f(uint16_t h) {
  uint32_t u = ((uint32_t)h) << 16;
  return __builtin_bit_cast(float, u);
}

// async global->LDS, 16B per lane. LDS dest must be wave-uniform base + lane*16.
__device__ __forceinline__ void gl_lds16(const void* gptr, void* lptr) {
  __builtin_amdgcn_global_load_lds(
      (const __attribute__((address_space(1))) uint32_t*)gptr,
      (__attribute__((address_space(3))) uint32_t*)lptr,
      16, 0, 0);
}

// T1: bijective XCD swizzle. Grid must be a multiple of 8 blocks.
// Consecutive-dispatched blocks round-robin over the 8 XCDs; this remap gives
// XCD x the CONTIGUOUS work range [x*perxcd, (x+1)*perxcd) so neighbor blocks
// (which share operand panels) hit the same private L2.
__device__ __forceinline__ int xcd_swz(int bid, int perxcd) {
  return (bid & 7) * perxcd + (bid >> 3);
}

// ---------------------------------------------------------------- convert f32->bf16
__global__ __launch_bounds__(256) void convert_bf16(
    const float* xq, const float* xkv, const float* wq, const float* wk,
    const float* wv, const float* wp,
    uint16_t* dxq, uint16_t* dxkv, uint16_t* dwq, uint16_t* dwk,
    uint16_t* dwv, uint16_t* dwp)
{
  int bid = blockIdx.x;
  const float* s; uint16_t* d; int base;
  if (bid < 6152)       { s = xq;  d = dxq;  base = bid; }
  else if (bid < 12304) { s = xkv; d = dxkv; base = bid - 6152; }
  else {
    int r = bid - 12304;
    int wsel = r >> 10; base = r & 1023;
    s = (wsel == 0) ? wq : (wsel == 1) ? wk : (wsel == 2) ? wv : wp;
    d = (wsel == 0) ? dwq : (wsel == 1) ? dwk : (wsel == 2) ? dwv : dwp;
  }
  int i = base * 256 + threadIdx.x;
  float4 f = ((const float4*)s)[i];
  u16x4 o;
  o[0] = f2bf(f.x); o[1] = f2bf(f.y); o[2] = f2bf(f.z); o[3] = f2bf(f.w);
  ((u16x4*)d)[i] = o;
}

// ---------------------------------------------------------------- GEMM mainloop
// 128x128 tile, BK=64, 16 K-iters, XOR-8 chunk-swizzled LDS (0 bank conflicts).
// T3+T4 minimum form: 2-deep pipeline, COUNTED vmcnt + raw s_barrier; vmcnt
// never drains to 0 inside the loop.

__device__ __forceinline__ void gemm_stage64(
    const uint16_t* const Aptr[4], const uint16_t* const Bptr[4],
    int k0, uint16_t* sA, uint16_t* sB, int tid)
{
  #pragma unroll
  for (int r = 0; r < 4; r++) {
    gl_lds16(Aptr[r] + k0, sA + (r * 256 + tid) * 8);
    gl_lds16(Bptr[r] + k0, sB + (r * 256 + tid) * 8);
  }
}

__device__ __forceinline__ void gemm_compute64(
    const uint16_t* sAc, const uint16_t* sBc, v4f acc[4][4],
    int rbase, int cbase, int quad, int l15)
{
  #pragma unroll
  for (int s = 0; s < 2; s++) {
    v8s af[4], bfv[4];
    #pragma unroll
    for (int i = 0; i < 4; i++) {
      int m = rbase + i * 16 + l15;
      af[i] = *(const v8s*)(sAc + m * 64 + (((s * 4 + quad) ^ (m & 7)) * 8));
    }
    #pragma unroll
    for (int j = 0; j < 4; j++) {
      int n = cbase + j * 16 + l15;
      bfv[j] = *(const v8s*)(sBc + n * 64 + (((s * 4 + quad) ^ (n & 7)) * 8));
    }
    #pragma unroll
    for (int i = 0; i < 4; i++)
      #pragma unroll
      for (int j = 0; j < 4; j++)
        acc[i][j] = __builtin_amdgcn_mfma_f32_16x16x32_bf16(af[i], bfv[j], acc[i][j], 0, 0, 0);
  }
}

__device__ __forceinline__ void gemm_mainloop64(
    const uint16_t* A, const uint16_t* W, int M, int row0, int col0,
    v4f acc[4][4], uint16_t* sA, uint16_t* sB)   // sA,sB each 2*128*64
{
  const int tid = threadIdx.x;
  const int lane = tid & 63, w = tid >> 6, quad = lane >> 4, l15 = lane & 15;
  const int rbase = (w >> 1) * 64, cbase = (w & 1) * 64;

  const uint16_t* Aptr[4];
  const uint16_t* Bptr[4];
  #pragma unroll
  for (int r = 0; r < 4; r++) {
    int c = r * 256 + tid;
    int row = c >> 3, qp = c & 7;
    int g = qp ^ (row & 7);
    Aptr[r] = A + (size_t)min(row0 + row, M - 1) * 1024 + g * 8;
    Bptr[r] = W + (size_t)(col0 + row) * 1024 + g * 8;
  }

  #pragma unroll
  for (int i = 0; i < 4; i++)
    #pragma unroll
    for (int j = 0; j < 4; j++) acc[i][j] = (v4f)0.0f;

  uint16_t* sA0 = sA;         uint16_t* sB0 = sB;
  uint16_t* sA1 = sA + 8192;  uint16_t* sB1 = sB + 8192;

  // prologue: stage tiles 0 and 1 (16 loads in flight per wave)
  gemm_stage64(Aptr, Bptr, 0,  sA0, sB0, tid);
  gemm_stage64(Aptr, Bptr, 64, sA1, sB1, tid);

  #pragma unroll 1
  for (int t = 0; t < 16; t++) {
    // Wait for THIS tile's 8 loads only; tile t+1's 8 stay in flight.
    if (t < 15) {
      asm volatile("s_waitcnt vmcnt(8)" ::: "memory");
    } else {
      asm volatile("s_waitcnt vmcnt(0)" ::: "memory");
    }
    __builtin_amdgcn_s_barrier();        // all waves' tile-t loads have landed
    uint16_t* cA = (t & 1) ? sA1 : sA0;
    uint16_t* cB = (t & 1) ? sB1 : sB0;
    gemm_compute64(cA, cB, acc, rbase, cbase, quad, l15);
    __builtin_amdgcn_s_barrier();        // all waves done reading buf[t&1]
    if (t + 2 < 16)
      gemm_stage64(Aptr, Bptr, (t + 2) * 64, cA, cB, tid);  // restage consumed buf
  }
}

// Fused QKV projection (Wqkv packed [3072][1024]; ct>>3 selects Q/K/V).
// Grid: 1176 blocks 1D, XCD-swizzled (147/XCD, ct-fastest -> A-panel L2 reuse).
__global__ __launch_bounds__(256) void gemm_qkv(
    const uint16_t* xq, const uint16_t* xkv, const uint16_t* Wqkv,
    const float* bq, const float* bk, const float* bv, const float* freqs,
    uint16_t* Q, uint16_t* K, uint16_t* V)
{
  __shared__ uint16_t sA[2 * 128 * 64];
  __shared__ uint16_t sB[2 * 128 * 64];
  const int swz = xcd_swz(blockIdx.x, 147);   // 1176 = 8*147
  const int ct = swz % 24, rt = swz / 24;
  const int z = ct >> 3;
  const int col0 = ct * 128, row0 = rt * 128;
  const uint16_t* A = (z == 0) ? xq : xkv;
  const float* bias  = (z == 0) ? bq : (z == 1 ? bk : bv);
  uint16_t* dst      = (z == 0) ? Q  : (z == 1 ? K  : V);

  v4f acc[4][4];
  gemm_mainloop64(A, Wqkv, NTOK, row0, col0, acc, sA, sB);

  const int tid = threadIdx.x;
  const int lane = tid & 63, w = tid >> 6, quad = lane >> 4, l15 = lane & 15;
  const int rbase = (w >> 1) * 64, cbase = (w & 1) * 64;
  #pragma unroll
  for (int i = 0; i < 4; i++) {
    #pragma unroll
    for (int reg = 0; reg < 4; reg++) {
      int n = row0 + rbase + i * 16 + quad * 4 + reg;
      bool ok = (n < NTOK);
      int nn = min(n, NTOK - 1);
      int b = nn / T_, t = nn % T_;
      float vj[4];
      #pragma unroll
      for (int j = 0; j < 4; j++)
        vj[j] = acc[i][j][reg] + bias[(col0 + cbase + j * 16 + l15) & 1023];
      if (z < 2) {
        float v0 = vj[0], v1 = vj[1];
        float p0 = __shfl_xor(v0, 1);
        float p1 = __shfl_xor(v1, 1);
        float f0 = freqs[t * 32 + l15];
        float f1 = freqs[t * 32 + 16 + l15];
        float s0, c0, s1, c1;
        __sincosf(f0, &s0, &c0);
        __sincosf(f1, &s1, &c1);
        if (l15 & 1) { vj[0] = v0 * c0 + p0 * s0; vj[1] = v1 * c1 + p1 * s1; }
        else         { vj[0] = v0 * c0 - p0 * s0; vj[1] = v1 * c1 - p1 * s1; }
      }
      if (z == 0) {
        #pragma unroll
        for (int j = 0; j < 4; j++) vj[j] *= 0.125f;
      }
      if (ok) {
        #pragma unroll
        for (int j = 0; j < 4; j++) {
          int col = col0 + cbase + j * 16 + l15;
          int h = (col >> 6) & 15, d = col & 63;
          dst[((size_t)(b * H_ + h) * T_ + t) * 64 + d] = f2bf(vj[j]);
        }
      }
    }
  }
}

// Output projection: f32 -> d_out [NTOK][1024]
// Grid: 392 blocks 1D, XCD-swizzled (49/XCD).
__global__ __launch_bounds__(256) void gemm_out(
    const uint16_t* Y, const uint16_t* wp, const float* bp, float* out)
{
  __shared__ uint16_t sA[2 * 128 * 64];
  __shared__ uint16_t sB[2 * 128 * 64];
  const int swz = xcd_swz(blockIdx.x, 49);    // 392 = 8*49
  const int ct = swz & 7, rt = swz >> 3;
  const int col0 = ct * 128, row0 = rt * 128;
  v4f acc[4][4];
  gemm_mainloop64(Y, wp, NTOK, row0, col0, acc, sA, sB);

  const int tid = threadIdx.x;
  const int lane = tid & 63, w = tid >> 6, quad = lane >> 4, l15 = lane & 15;
  const int rbase = (w >> 1) * 64, cbase = (w & 1) * 64;
  #pragma unroll
  for (int i = 0; i < 4; i++) {
    #pragma unroll
    for (int reg = 0; reg < 4; reg++) {
      int n = row0 + rbase + i * 16 + quad * 4 + reg;
      if (n < NTOK) {
        #pragma unroll
        for (int j = 0; j < 4; j++) {
          int col = col0 + cbase + j * 16 + l15;
          out[(size_t)n * 1024 + col] = acc[i][j][reg] + bp[col];
        }
      }
    }
  }
}

// ---------------------------------------------------------------- V transpose
// Vb [bh][T][64] -> Vt [bh][64][TP_]. 64x64 tiles, XOR-swizzled LDS (8 KB).
// Both global sides coalesced (128B runs); LDS read side conflict-free.
__global__ __launch_bounds__(256) void transpose_v(const uint16_t* Vb, uint16_t* Vt)
{
  __shared__ uint16_t sT[64 * 64];
  const int tid = threadIdx.x;
  const int t0 = blockIdx.x * 64, bh = blockIdx.y;
  const uint16_t* src = Vb + (size_t)bh * T_ * 64;
  #pragma unroll
  for (int r = 0; r < 2; r++) {
    int task = r * 256 + tid;
    int t = task >> 3, oc = task & 7;
    int gt = min(t0 + t, T_ - 1);
    u16x8 v = *(const u16x8*)(src + (size_t)gt * 64 + oc * 8);
    int p = oc ^ (t & 7) ^ ((t >> 3) & 7);
    *(u16x8*)(sT + t * 64 + p * 8) = v;
  }
  __syncthreads();
  uint16_t* dst = Vt + (size_t)bh * 64 * TP_;
  #pragma unroll
  for (int r = 0; r < 2; r++) {
    int task = r * 256 + tid;
    int o = task & 7, d = task >> 3;
    u16x8 v;
    #pragma unroll
    for (int k = 0; k < 8; k++) {
      int t = o * 8 + k;
      int p = (d >> 3) ^ k ^ o;
      v[k] = sT[t * 64 + p * 8 + (d & 7)];
    }
    *(u16x8*)(dst + (size_t)d * TP_ + t0 + o * 8) = v;
  }
}

// ---------------------------------------------------------------- flash attention
// 4 waves x 16 q-rows; 128-key tiles; fixed-max softmax.
// sK [128 keys][64 d] and sVT [64 d][128 keys] both gl_lds16-staged with
// XOR-8 chunk swizzle (2-way bank aliasing = free). sP per-wave [16][136].
// Grid: 1664 blocks 1D, XCD-swizzled (208/XCD) -> all 13 q-tiles of a bh on
// one XCD, K/V panels L2-resident across the q-sweep.
__global__ __launch_bounds__(256) void attn(
    const uint16_t* Q, const uint16_t* K, const uint16_t* Vt, uint16_t* Y)
{
  __shared__ uint16_t sK[128 * 64];
  __shared__ uint16_t sVT[64 * 128];
  __shared__ uint16_t sP[4 * 16 * 136];

  const int tid = threadIdx.x;
  const int lane = tid & 63, w = tid >> 6, quad = lane >> 4, l15 = lane & 15;
  const int swz = xcd_swz(blockIdx.x, 208);   // 1664 = 8*208
  const int qt = swz % 13, bh = swz / 13;
  const int b = bh >> 4, h = bh & 15;
  const int q0 = qt * 64;

  const uint16_t* Qb = Q + (size_t)bh * T_ * 64;
  const uint16_t* Kb = K + (size_t)bh * T_ * 64;
  const uint16_t* Vtb = Vt + (size_t)bh * 64 * TP_;

  const int qr = min(q0 + w * 16 + l15, T_ - 1);
  v8s aq0 = *(const v8s*)(Qb + (size_t)qr * 64 + quad * 8);
  v8s aq1 = *(const v8s*)(Qb + (size_t)qr * 64 + 32 + quad * 8);

  float l_r[4] = {0.f, 0.f, 0.f, 0.f};
  v4f o[4];
  #pragma unroll
  for (int r = 0; r < 4; r++) o[r] = (v4f)0.0f;

  const int kend = min(T_, q0 + 319);       // max col = 255 + (q0+63)
  const int nkt = (kend + 127) >> 7;

  for (int kt = 0; kt < nkt; kt++) {
    const int k0 = kt * 128;
    // --- stage K tile (natural layout, XOR-8 swizzle)
    #pragma unroll
    for (int r = 0; r < 4; r++) {
      int c = r * 256 + tid;
      int key = c >> 3, qp = c & 7;
      int g = qp ^ (key & 7);
      int gk = min(k0 + key, T_ - 1);
      gl_lds16(Kb + (size_t)gk * 64 + g * 8, sK + c * 8);
    }
    // --- stage V^T tile (pre-transposed global, XOR-8 swizzle on 16 chunks/row)
    #pragma unroll
    for (int r = 0; r < 4; r++) {
      int c = r * 256 + tid;
      int d = c >> 4, p = c & 15;
      int g = (p & 8) | ((p ^ d) & 7);
      gl_lds16(Vtb + (size_t)d * TP_ + k0 + g * 8, sVT + c * 8);
    }
    __syncthreads();

    // --- S = Q K^T (Q pre-scaled by 1/8): 8 key frags x 2 k-steps
    v4f s[8];
    #pragma unroll
    for (int cb = 0; cb < 8; cb++) {
      int key_l = cb * 16 + l15;
      v8s b0 = *(const v8s*)(sK + (key_l * 8 + ((quad) ^ (key_l & 7))) * 8);
      v8s b1 = *(const v8s*)(sK + (key_l * 8 + ((4 + quad) ^ (key_l & 7))) * 8);
      v4f zz = (v4f)0.0f;
      zz = __builtin_amdgcn_mfma_f32_16x16x32_bf16(aq0, b0, zz, 0, 0, 0);
      zz = __builtin_amdgcn_mfma_f32_16x16x32_bf16(aq1, b1, zz, 0, 0, 0);
      s[cb] = zz;
    }

    // --- fixed-max softmax: P = exp(S), masked -> 0
    uint16_t* pw = sP + w * (16 * 136);
    const int qrow_base = q0 + w * 16 + quad * 4;
    const bool full = (k0 + 128 <= COND_ + q0) && (k0 + 128 <= T_);
    if (full) {
      #pragma unroll
      for (int reg = 0; reg < 4; reg++) {
        float rs = 0.f;
        #pragma unroll
        for (int cb = 0; cb < 8; cb++) {
          float pv = __expf(s[cb][reg]);
          uint16_t pb = f2bf(pv);
          rs += bf2f(pb);
          pw[(quad * 4 + reg) * 136 + cb * 16 + l15] = pb;
        }
        #pragma unroll
        for (int off = 1; off < 16; off <<= 1) rs += __shfl_xor(rs, off);
        l_r[reg] += rs;
      }
    } else {
      #pragma unroll
      for (int reg = 0; reg < 4; reg++) {
        int lim = min(COND_ + qrow_base + reg, T_);
        float rs = 0.f;
        #pragma unroll
        for (int cb = 0; cb < 8; cb++) {
          int key = k0 + cb * 16 + l15;
          float pv = (key < lim) ? __expf(s[cb][reg]) : 0.f;
          uint16_t pb = f2bf(pv);
          rs += bf2f(pb);
          pw[(quad * 4 + reg) * 136 + cb * 16 + l15] = pb;
        }
        #pragma unroll
        for (int off = 1; off < 16; off <<= 1) rs += __shfl_xor(rs, off);
        l_r[reg] += rs;
      }
    }

    // --- O += P V (sP wave-private; in-wave lgkm ordering suffices)
    #pragma unroll
    for (int ks = 0; ks < 4; ks++) {
      v8s ap = *(const v8s*)(pw + l15 * 136 + ks * 32 + quad * 8);
      #pragma unroll
      for (int cbd = 0; cbd < 4; cbd++) {
        int d = cbd * 16 + l15;
        v8s bv = *(const v8s*)(sVT + d * 128 + (((ks * 4 + quad) ^ (d & 7)) * 8));
        o[cbd] = __builtin_amdgcn_mfma_f32_16x16x32_bf16(ap, bv, o[cbd], 0, 0, 0);
      }
    }
    __syncthreads();   // safe to restage K/V next iter
  }

  // --- epilogue: O / l -> Y [B][T][C] bf16
  #pragma unroll
  for (int reg = 0; reg < 4; reg++) {
    int t = q0 + w * 16 + quad * 4 + reg;
    if (t < T_) {
      float inv = 1.0f / l_r[reg];
      #pragma unroll
      for (int cbd = 0; cbd < 4; cbd++) {
        int d = cbd * 16 + l15;
        Y[((size_t)(b * T_ + t)) * C_ + h * 64 + d] = f2bf(o[cbd][reg] * inv);
      }
    }
  }
}

// ---------------------------------------------------------------- launch
extern "C" void kernel_launch(void* const* d_in, const int* in_sizes, int n_in,
                              void* d_out, int out_size, void* d_ws, size_t ws_size,
                              hipStream_t stream)
{
  const float* x_q   = (const float*)d_in[0];
  const float* x_kv  = (const float*)d_in[1];
  const float* freqs = (const float*)d_in[2];
  const float* Wq = (const float*)d_in[3];
  const float* bq = (const float*)d_in[4];
  const float* Wk = (const float*)d_in[5];
  const float* bk = (const float*)d_in[6];
  const float* Wv = (const float*)d_in[7];
  const float* bv = (const float*)d_in[8];
  const float* Wp = (const float*)d_in[9];
  const float* bp = (const float*)d_in[10];
  float* out = (float*)d_out;

  const size_t SZX = (size_t)NTOK * C_;     // 6,299,648
  const size_t SZW = (size_t)C_ * C_;       // 1,048,576
  uint16_t* ws = (uint16_t*)d_ws;
  // layout: [xq_bf | xkv_bf | wq wk wv wp | Qb | Kb | Vb]  (71.4 MB total)
  uint16_t* xq_bf  = ws;
  uint16_t* xkv_bf = xq_bf + SZX;
  uint16_t* wq_bf  = xkv_bf + SZX;   // wq/wk/wv contiguous = packed Wqkv[3072][1024]
  uint16_t* wk_bf  = wq_bf + SZW;
  uint16_t* wv_bf  = wk_bf + SZW;
  uint16_t* wp_bf  = wv_bf + SZW;
  uint16_t* Qb = wp_bf + SZW;
  uint16_t* Kb = Qb + SZX;
  uint16_t* Vb = Kb + SZX;
  // aliases (lifetimes disjoint on the serial stream):
  uint16_t* Vt = ws;                 // 128*64*896 = 7.34M elems over dead xq/xkv
  uint16_t* Yb = Vb;                 // attn output over dead natural-V

  convert_bf16<<<dim3(16400), 256, 0, stream>>>(
      x_q, x_kv, Wq, Wk, Wv, Wp, xq_bf, xkv_bf, wq_bf, wk_bf, wv_bf, wp_bf);

  gemm_qkv<<<dim3(1176), 256, 0, stream>>>(
      xq_bf, xkv_bf, wq_bf, bq, bk, bv, freqs, Qb, Kb, Vb);

  transpose_v<<<dim3(13, BH_), 256, 0, stream>>>(Vb, Vt);

  attn<<<dim3(1664), 256, 0, stream>>>(Qb, Kb, Vt, Yb);

  gemm_out<<<dim3(392), 256, 0, stream>>>(Yb, wp_bf, bp, out);
}